// Round 9
// baseline (62.531 us; speedup 1.0000x reference)
//
#include <hip/hip_runtime.h>
#include <math.h>

#define NB 4
#define NL 128
#define NT 512
#define NS 128
#define HD 256
#define TILE_M 32
#define NTHREADS 512
#define TPB 16                      // tiles per block
#define GRID 512                    // (NB*NL*NT/TILE_M)/TPB

typedef __bf16 bf16x8 __attribute__((ext_vector_type(8)));
typedef __bf16 bf16x4 __attribute__((ext_vector_type(4)));
typedef float  f32x4  __attribute__((ext_vector_type(4)));

__global__ __launch_bounds__(NTHREADS) void fused_gvp_kernel(
    const float* __restrict__ indice,   // [B,3,NL,NT]
    const float* __restrict__ lpos,     // [B,NL,3]
    const float* __restrict__ tpos,     // [B,NT,3]
    const float* __restrict__ rotor,    // [B]
    const float* __restrict__ lrad,     // [B,NL]
    const float* __restrict__ trad,     // [B,NT]
    const float* __restrict__ lnm,      // [B,NL]
    const float* __restrict__ tnm,      // [B,NT]
    const float* __restrict__ hcat,     // [B,NL,NT,HD]
    const float* __restrict__ AW1, const float* __restrict__ Ab1,
    const float* __restrict__ AW2, const float* __restrict__ Ab2,
    const float* __restrict__ BW1, const float* __restrict__ Bb1,
    const float* __restrict__ BW2, const float* __restrict__ Bb2,
    const float* __restrict__ hbc, const float* __restrict__ hyc,
    const float* __restrict__ rcc,
    float* __restrict__ out)            // [NB*4], zeroed each call
{
    __shared__ __align__(16) __bf16 hbuf[2][TILE_M * HD];   // 32 KiB, swizzled
    __shared__ __align__(16) float  part[TPB][TILE_M][8];   // 16 KiB
    __shared__ float red[8][4];

    const int tid  = threadIdx.x;
    const int wv   = tid >> 6;
    const int lane = tid & 63;
    const int l15  = lane & 15;
    const int kg   = lane >> 4;

    const size_t base = (size_t)blockIdx.x * (TPB * TILE_M * HD);

    float4 stg[4];

#define LOADT(t) { \
        const float* src = hcat + base + (size_t)(t) * (TILE_M * HD); \
        _Pragma("unroll") \
        for (int i = 0; i < 4; ++i) \
            stg[i] = *(const float4*)(src + ((tid >> 6) + i * 8) * HD + (tid & 63) * 4); }

#define STORET(bi) { \
        char* lw = (char*)&hbuf[bi][0]; \
        _Pragma("unroll") \
        for (int i = 0; i < 4; ++i) { \
            int row = (tid >> 6) + i * 8; \
            int cb  = (tid & 63) * 8; \
            bf16x4 p; \
            p[0] = (__bf16)stg[i].x; p[1] = (__bf16)stg[i].y; \
            p[2] = (__bf16)stg[i].z; p[3] = (__bf16)stg[i].w; \
            *(bf16x4*)(lw + row * 512 + (cb ^ ((row & 15) << 4))) = p; } }

// raw barrier: publish LDS writes, do NOT drain vmcnt (loads stay in flight)
#define RAW_BARRIER() { \
        asm volatile("s_waitcnt lgkmcnt(0)" ::: "memory"); \
        __builtin_amdgcn_s_barrier(); \
        __builtin_amdgcn_sched_barrier(0); }

    // ---- issue tile-0 loads first (latency hides under weight setup) ----
    LOADT(0)

    // ---- weights: wave wv owns 32 hidden cols of A (wv<4) or B MLP ----
    const bool  isA = (wv < 4);
    const float* W1 = isA ? AW1 : BW1;
    const float* W2 = isA ? AW2 : BW2;
    const float* b1 = isA ? Ab1 : Bb1;
    const int nbase = (wv & 3) * 32;

    // A-operand fragments: lane l15 = hidden row, k = kg*8+i within K=32 window
    bf16x8 wreg[2][8];                  // [hf][kk]
    #pragma unroll
    for (int hf = 0; hf < 2; ++hf) {
        int n = nbase + hf * 16 + l15;
        #pragma unroll
        for (int kk = 0; kk < 8; ++kk) {
            int k0 = kk * 32 + kg * 8;
            bf16x8 wvv;
            #pragma unroll
            for (int i = 0; i < 8; ++i)
                wvv[i] = (__bf16)W1[(k0 + i) * NS + n];
            wreg[hf][kk] = wvv;
        }
    }
    // per-lane bias/W2 for hidden = nbase + hf*16 + kg*4 + j
    float b1v[2][4], w2v[2][4];
    #pragma unroll
    for (int hf = 0; hf < 2; ++hf)
        #pragma unroll
        for (int j = 0; j < 4; ++j) {
            int h = nbase + hf * 16 + kg * 4 + j;
            b1v[hf][j] = b1[h];
            w2v[hf][j] = W2[h];
        }

    // prologue: buf0 <- tile0 (waits tile0 loads), issue tile1, publish buf0
    STORET(0)
    LOADT(1)
    RAW_BARRIER()

    for (int it = 0; it < TPB; ++it) {
        // stage tile it+1 (loads issued a full phase ago -> wait ~free)
        if (it + 1 < TPB) {
            STORET((it + 1) & 1)
        }
        // issue tile it+2 loads; they stay in flight across the raw barrier
        if (it + 2 < TPB) {
            LOADT(it + 2)
        }

        // ---- MFMA K-loop: D[hidden 16 x rows 16], A=weights(reg), B=hcat(LDS) ----
        f32x4 acc[2][2] = {};           // [rf][hf]
        const char* lb = (const char*)&hbuf[it & 1][0];
        #pragma unroll
        for (int kk = 0; kk < 8; ++kk) {
            #pragma unroll
            for (int rf = 0; rf < 2; ++rf) {
                int row = rf * 16 + l15;
                bf16x8 bfrag = *(const bf16x8*)(lb + row * 512 + ((kk * 64 + kg * 16) ^ ((row & 15) << 4)));
                acc[rf][0] = __builtin_amdgcn_mfma_f32_16x16x32_bf16(wreg[0][kk], bfrag, acc[rf][0], 0, 0, 0);
                acc[rf][1] = __builtin_amdgcn_mfma_f32_16x16x32_bf16(wreg[1][kk], bfrag, acc[rf][1], 0, 0, 0);
            }
        }

        // ---- hidden reduce: in-lane over regs, 2 shfl over kg groups ----
        #pragma unroll
        for (int rf = 0; rf < 2; ++rf) {
            float p = 0.f;
            #pragma unroll
            for (int hf = 0; hf < 2; ++hf)
                #pragma unroll
                for (int j = 0; j < 4; ++j)
                    p += fmaxf(acc[rf][hf][j] + b1v[hf][j], 0.f) * w2v[hf][j];
            p += __shfl_xor(p, 16, 64);
            p += __shfl_xor(p, 32, 64);
            if (kg == 0) part[it][rf * 16 + l15][wv] = p;
        }

        RAW_BARRIER()   // publish buf[(it+1)&1] + part[it]; loads stay in flight
    }

    __syncthreads();   // full fence before epilogue reads part[]

    // ---- epilogue: one pair-row per thread (block covers one (b,l), t=tid) ----
    {
        const f32x4* pp = (const f32x4*)&part[tid >> 5][tid & 31][0];
        f32x4 pa = pp[0], pb = pp[1];
        float sA = Ab2[0] + pa[0] + pa[1] + pa[2] + pa[3];
        float sB = Bb2[0] + pb[0] + pb[1] + pb[2] + pb[3];

        float aw = 0.0178f + 0.0178f / (1.f + expf(-sA));   // sigmoid*(MAX-MIN)+MIN
        float bp = tanhf(sB) * 0.2f;

        const int g = blockIdx.x * (TPB * TILE_M) + tid;    // global pair index
        const int b = g >> 16;
        const int l = (g >> 9) & 127;                       // uniform per block
        const int t = g & 511;                              // == tid

        const float* lp = lpos + ((size_t)b * NL + l) * 3;
        const float* tp = tpos + ((size_t)b * NT + t) * 3;
        float dx = lp[0] - tp[0], dy = lp[1] - tp[1], dz = lp[2] - tp[2];
        float dm = sqrtf(dx * dx + dy * dy + dz * dz + 1e-10f);
        if (dm < 0.5f) dm = 1e10f;

        float dm0 = lrad[b * NL + l] + trad[b * NT + t] + bp;
        float ddm = dm - dm0;

        const size_t ib = (((size_t)b * 3) * NL + l) * NT + t;
        float i0 = indice[ib];
        float i1 = indice[ib + (size_t)NL * NT];
        float i2 = indice[ib + 2 * (size_t)NL * NT];

        const float kInv = -1.f / 0.7f;
        float ehb = fminf(fmaxf(ddm * i0 * kInv, 0.f), 1.f);
        float emt = fminf(fmaxf(ddm * i1 * kInv, 0.f), 1.f);
        float ehp = fminf(fmaxf((1.5f - ddm) * i2, 0.f), 1.f);

        float dm0v = (dm0 < 1e-4f) ? 1.f : dm0;
        float ratio = dm0v / dm;
        float r2 = ratio * ratio;
        float r6 = r2 * r2 * r2;
        float ve = fminf(r6 * r6 - 2.f * r6, 100.f);
        ve *= lnm[b * NL + l] * tnm[b * NT + t];
        float evdw = aw * ve;

        #pragma unroll
        for (int off = 32; off > 0; off >>= 1) {
            evdw += __shfl_xor(evdw, off, 64);
            ehb  += __shfl_xor(ehb,  off, 64);
            emt  += __shfl_xor(emt,  off, 64);
            ehp  += __shfl_xor(ehp,  off, 64);
        }
        if (lane == 0) {
            red[wv][0] = evdw; red[wv][1] = ehb;
            red[wv][2] = emt;  red[wv][3] = ehp;
        }
    }
    __syncthreads();

    // ---- commutative finalize: scale this block's partials, atomicAdd to out ----
    if (tid < 4) {
        const int c = tid;
        float v = 0.f;
        #pragma unroll
        for (int w = 0; w < 8; ++w) v += red[w][c];
        const int b = blockIdx.x >> 7;              // 128 blocks per batch
        float s    = 1.f / (1.f + rcc[0] * rcc[0] * rotor[b]);
        float coef = (c == 0) ? 1.f
                   : (c == 3) ? -(hyc[0] * hyc[0])
                              : -(hbc[0] * hbc[0]);
        atomicAdd(out + b * 4 + c, coef * s * v);
    }
}

extern "C" void kernel_launch(void* const* d_in, const int* in_sizes, int n_in,
                              void* d_out, int out_size, void* d_ws, size_t ws_size,
                              hipStream_t stream)
{
    const float* indice = (const float*)d_in[0];
    const float* lpos   = (const float*)d_in[1];
    const float* tpos   = (const float*)d_in[2];
    const float* rotor  = (const float*)d_in[3];
    const float* lrad   = (const float*)d_in[4];
    const float* trad   = (const float*)d_in[5];
    const float* lnm    = (const float*)d_in[6];
    const float* tnm    = (const float*)d_in[7];
    const float* hcat   = (const float*)d_in[8];
    const float* AW1    = (const float*)d_in[9];
    const float* Ab1    = (const float*)d_in[10];
    const float* AW2    = (const float*)d_in[11];
    const float* Ab2    = (const float*)d_in[12];
    const float* BW1    = (const float*)d_in[13];
    const float* Bb1    = (const float*)d_in[14];
    const float* BW2    = (const float*)d_in[15];
    const float* Bb2    = (const float*)d_in[16];
    const float* hbc    = (const float*)d_in[17];
    const float* hyc    = (const float*)d_in[18];
    const float* rcc    = (const float*)d_in[19];

    float* out = (float*)d_out;

    hipMemsetAsync(out, 0, NB * 4 * sizeof(float), stream);
    hipLaunchKernelGGL(fused_gvp_kernel, dim3(GRID), dim3(NTHREADS), 0, stream,
                       indice, lpos, tpos, rotor, lrad, trad, lnm, tnm, hcat,
                       AW1, Ab1, AW2, Ab2, BW1, Bb1, BW2, Bb2,
                       hbc, hyc, rcc, out);
}

// Round 10
// 58.947 us; speedup vs baseline: 1.0608x; 1.0608x over previous
//
#include <hip/hip_runtime.h>
#include <math.h>

#define NB 4
#define NL 128
#define NT 512
#define NS 128
#define HD 256
#define TILE_M 32
#define NTHREADS 512
#define TPB 16                      // tiles per block
#define GRID 512                    // (NB*NL*NT/TILE_M)/TPB

typedef __bf16 bf16x8 __attribute__((ext_vector_type(8)));
typedef __bf16 bf16x4 __attribute__((ext_vector_type(4)));
typedef float  f32x4  __attribute__((ext_vector_type(4)));

__global__ __launch_bounds__(NTHREADS) void fused_gvp_kernel(
    const float* __restrict__ indice,   // [B,3,NL,NT]
    const float* __restrict__ lpos,     // [B,NL,3]
    const float* __restrict__ tpos,     // [B,NT,3]
    const float* __restrict__ lrad,     // [B,NL]
    const float* __restrict__ trad,     // [B,NT]
    const float* __restrict__ lnm,      // [B,NL]
    const float* __restrict__ tnm,      // [B,NT]
    const float* __restrict__ hcat,     // [B,NL,NT,HD]
    const float* __restrict__ AW1, const float* __restrict__ Ab1,
    const float* __restrict__ AW2, const float* __restrict__ Ab2,
    const float* __restrict__ BW1, const float* __restrict__ Bb1,
    const float* __restrict__ BW2, const float* __restrict__ Bb2,
    float* __restrict__ ws)             // [GRID*4] per-block partials
{
    __shared__ __align__(16) __bf16 hbuf[2][TILE_M * HD];   // 32 KiB, swizzled
    __shared__ __align__(16) float  part[TPB][TILE_M][8];   // 16 KiB
    __shared__ float red[8][4];

    const int tid  = threadIdx.x;
    const int wv   = tid >> 6;
    const int lane = tid & 63;
    const int l15  = lane & 15;
    const int kg   = lane >> 4;

    const size_t base = (size_t)blockIdx.x * (TPB * TILE_M * HD);

    float4 stg[4];

#define LOADT(t) { \
        const float* src = hcat + base + (size_t)(t) * (TILE_M * HD); \
        _Pragma("unroll") \
        for (int i = 0; i < 4; ++i) \
            stg[i] = *(const float4*)(src + ((tid >> 6) + i * 8) * HD + (tid & 63) * 4); }

#define STORET(bi) { \
        char* lw = (char*)&hbuf[bi][0]; \
        _Pragma("unroll") \
        for (int i = 0; i < 4; ++i) { \
            int row = (tid >> 6) + i * 8; \
            int cb  = (tid & 63) * 8; \
            bf16x4 p; \
            p[0] = (__bf16)stg[i].x; p[1] = (__bf16)stg[i].y; \
            p[2] = (__bf16)stg[i].z; p[3] = (__bf16)stg[i].w; \
            *(bf16x4*)(lw + row * 512 + (cb ^ ((row & 15) << 4))) = p; } }

// raw barrier: publish LDS writes, do NOT drain vmcnt (loads stay in flight)
#define RAW_BARRIER() { \
        asm volatile("s_waitcnt lgkmcnt(0)" ::: "memory"); \
        __builtin_amdgcn_s_barrier(); \
        __builtin_amdgcn_sched_barrier(0); }

    // ---- issue tile-0 loads first (latency hides under weight setup) ----
    LOADT(0)

    // ---- weights: wave wv owns 32 hidden cols of A (wv<4) or B MLP ----
    const bool  isA = (wv < 4);
    const float* W1 = isA ? AW1 : BW1;
    const float* W2 = isA ? AW2 : BW2;
    const float* b1 = isA ? Ab1 : Bb1;
    const int nbase = (wv & 3) * 32;

    // A-operand fragments: lane l15 = hidden row, k = kg*8+i within K=32 window
    bf16x8 wreg[2][8];                  // [hf][kk]
    #pragma unroll
    for (int hf = 0; hf < 2; ++hf) {
        int n = nbase + hf * 16 + l15;
        #pragma unroll
        for (int kk = 0; kk < 8; ++kk) {
            int k0 = kk * 32 + kg * 8;
            bf16x8 wvv;
            #pragma unroll
            for (int i = 0; i < 8; ++i)
                wvv[i] = (__bf16)W1[(k0 + i) * NS + n];
            wreg[hf][kk] = wvv;
        }
    }
    // per-lane bias/W2 for hidden = nbase + hf*16 + kg*4 + j
    float b1v[2][4], w2v[2][4];
    #pragma unroll
    for (int hf = 0; hf < 2; ++hf)
        #pragma unroll
        for (int j = 0; j < 4; ++j) {
            int h = nbase + hf * 16 + kg * 4 + j;
            b1v[hf][j] = b1[h];
            w2v[hf][j] = W2[h];
        }

    // ---- hoist epilogue loads: depend only on blockIdx/tid; issue now,
    //      consume after the main loop (latency fully hidden) ----
    const int g_ = blockIdx.x * (TPB * TILE_M) + tid;   // global pair index
    const int b_ = g_ >> 16;
    const int l_ = (g_ >> 9) & 127;                     // uniform per block
    const int t_ = g_ & 511;                            // == tid
    const float* lp_ = lpos + ((size_t)b_ * NL + l_) * 3;
    const float* tp_ = tpos + ((size_t)b_ * NT + t_) * 3;
    float e_lp0 = lp_[0], e_lp1 = lp_[1], e_lp2 = lp_[2];
    float e_tp0 = tp_[0], e_tp1 = tp_[1], e_tp2 = tp_[2];
    float e_rad = lrad[b_ * NL + l_] + trad[b_ * NT + t_];
    float e_nm  = lnm[b_ * NL + l_] * tnm[b_ * NT + t_];
    const size_t ib_ = (((size_t)b_ * 3) * NL + l_) * NT + t_;
    float e_i0 = indice[ib_];
    float e_i1 = indice[ib_ + (size_t)NL * NT];
    float e_i2 = indice[ib_ + 2 * (size_t)NL * NT];
    float e_b2A = Ab2[0], e_b2B = Bb2[0];

    // prologue: buf0 <- tile0 (waits tile0 loads), issue tile1, publish buf0
    STORET(0)
    LOADT(1)
    RAW_BARRIER()

    for (int it = 0; it < TPB; ++it) {
        // stage tile it+1 (loads issued a full phase ago -> wait ~free)
        if (it + 1 < TPB) {
            STORET((it + 1) & 1)
        }
        // issue tile it+2 loads; they stay in flight across the raw barrier
        if (it + 2 < TPB) {
            LOADT(it + 2)
        }

        // ---- MFMA K-loop: D[hidden 16 x rows 16], A=weights(reg), B=hcat(LDS) ----
        f32x4 acc[2][2] = {};           // [rf][hf]
        const char* lb = (const char*)&hbuf[it & 1][0];
        #pragma unroll
        for (int kk = 0; kk < 8; ++kk) {
            #pragma unroll
            for (int rf = 0; rf < 2; ++rf) {
                int row = rf * 16 + l15;
                bf16x8 bfrag = *(const bf16x8*)(lb + row * 512 + ((kk * 64 + kg * 16) ^ ((row & 15) << 4)));
                acc[rf][0] = __builtin_amdgcn_mfma_f32_16x16x32_bf16(wreg[0][kk], bfrag, acc[rf][0], 0, 0, 0);
                acc[rf][1] = __builtin_amdgcn_mfma_f32_16x16x32_bf16(wreg[1][kk], bfrag, acc[rf][1], 0, 0, 0);
            }
        }

        // ---- hidden reduce: in-lane over regs, 2 shfl over kg groups ----
        #pragma unroll
        for (int rf = 0; rf < 2; ++rf) {
            float p = 0.f;
            #pragma unroll
            for (int hf = 0; hf < 2; ++hf)
                #pragma unroll
                for (int j = 0; j < 4; ++j)
                    p += fmaxf(acc[rf][hf][j] + b1v[hf][j], 0.f) * w2v[hf][j];
            p += __shfl_xor(p, 16, 64);
            p += __shfl_xor(p, 32, 64);
            if (kg == 0) part[it][rf * 16 + l15][wv] = p;
        }

        RAW_BARRIER()   // publish buf[(it+1)&1] + part[it]; loads stay in flight
    }

    __syncthreads();   // full fence before epilogue reads part[]

    // ---- epilogue: one pair-row per thread; all globals pre-loaded ----
    {
        const f32x4* pp = (const f32x4*)&part[tid >> 5][tid & 31][0];
        f32x4 pa = pp[0], pb = pp[1];
        float sA = e_b2A + pa[0] + pa[1] + pa[2] + pa[3];
        float sB = e_b2B + pb[0] + pb[1] + pb[2] + pb[3];

        float aw = 0.0178f + 0.0178f / (1.f + expf(-sA));   // sigmoid*(MAX-MIN)+MIN
        float bp = tanhf(sB) * 0.2f;

        float dx = e_lp0 - e_tp0, dy = e_lp1 - e_tp1, dz = e_lp2 - e_tp2;
        float dm = sqrtf(dx * dx + dy * dy + dz * dz + 1e-10f);
        if (dm < 0.5f) dm = 1e10f;

        float dm0 = e_rad + bp;
        float ddm = dm - dm0;

        const float kInv = -1.f / 0.7f;
        float ehb = fminf(fmaxf(ddm * e_i0 * kInv, 0.f), 1.f);
        float emt = fminf(fmaxf(ddm * e_i1 * kInv, 0.f), 1.f);
        float ehp = fminf(fmaxf((1.5f - ddm) * e_i2, 0.f), 1.f);

        float dm0v = (dm0 < 1e-4f) ? 1.f : dm0;
        float ratio = dm0v / dm;
        float r2 = ratio * ratio;
        float r6 = r2 * r2 * r2;
        float ve = fminf(r6 * r6 - 2.f * r6, 100.f);
        ve *= e_nm;
        float evdw = aw * ve;

        #pragma unroll
        for (int off = 32; off > 0; off >>= 1) {
            evdw += __shfl_xor(evdw, off, 64);
            ehb  += __shfl_xor(ehb,  off, 64);
            emt  += __shfl_xor(emt,  off, 64);
            ehp  += __shfl_xor(ehp,  off, 64);
        }
        if (lane == 0) {
            red[wv][0] = evdw; red[wv][1] = ehb;
            red[wv][2] = emt;  red[wv][3] = ehp;
        }
    }
    __syncthreads();
    if (tid < 4) {
        float v = 0.f;
        #pragma unroll
        for (int w = 0; w < 8; ++w) v += red[w][tid];
        ws[blockIdx.x * 4 + tid] = v;   // direct write, no atomics/memset
    }
}

__global__ __launch_bounds__(NTHREADS) void finalize_kernel(
    const float* __restrict__ ws,       // [GRID][4]
    const float* __restrict__ rotor,
    const float* __restrict__ hbc,
    const float* __restrict__ hyc,
    const float* __restrict__ rcc,
    float* __restrict__ out)            // [NB][4]
{
    __shared__ float red2[8][4];
    const int tid  = threadIdx.x;       // 512 threads; thread t owns block t
    const int wv   = tid >> 6;
    const int lane = tid & 63;

    f32x4 v = *(const f32x4*)(ws + tid * 4);
    #pragma unroll
    for (int off = 32; off > 0; off >>= 1) {
        v[0] += __shfl_xor(v[0], off, 64);
        v[1] += __shfl_xor(v[1], off, 64);
        v[2] += __shfl_xor(v[2], off, 64);
        v[3] += __shfl_xor(v[3], off, 64);
    }
    if (lane == 0) { red2[wv][0] = v[0]; red2[wv][1] = v[1]; red2[wv][2] = v[2]; red2[wv][3] = v[3]; }
    __syncthreads();
    if (tid < 16) {
        int b = tid >> 2, c = tid & 3;  // batch b = waves 2b, 2b+1 (128 blocks each)
        float sum = red2[2 * b][c] + red2[2 * b + 1][c];
        float s   = 1.f / (1.f + rcc[0] * rcc[0] * rotor[b]);
        float coef = (c == 0) ? 1.f
                   : (c == 3) ? -(hyc[0] * hyc[0])
                              : -(hbc[0] * hbc[0]);
        out[b * 4 + c] = coef * sum * s;
    }
}

extern "C" void kernel_launch(void* const* d_in, const int* in_sizes, int n_in,
                              void* d_out, int out_size, void* d_ws, size_t ws_size,
                              hipStream_t stream)
{
    const float* indice = (const float*)d_in[0];
    const float* lpos   = (const float*)d_in[1];
    const float* tpos   = (const float*)d_in[2];
    const float* rotor  = (const float*)d_in[3];
    const float* lrad   = (const float*)d_in[4];
    const float* trad   = (const float*)d_in[5];
    const float* lnm    = (const float*)d_in[6];
    const float* tnm    = (const float*)d_in[7];
    const float* hcat   = (const float*)d_in[8];
    const float* AW1    = (const float*)d_in[9];
    const float* Ab1    = (const float*)d_in[10];
    const float* AW2    = (const float*)d_in[11];
    const float* Ab2    = (const float*)d_in[12];
    const float* BW1    = (const float*)d_in[13];
    const float* Bb1    = (const float*)d_in[14];
    const float* BW2    = (const float*)d_in[15];
    const float* Bb2    = (const float*)d_in[16];
    const float* hbc    = (const float*)d_in[17];
    const float* hyc    = (const float*)d_in[18];
    const float* rcc    = (const float*)d_in[19];

    float* ws  = (float*)d_ws;
    float* out = (float*)d_out;

    hipLaunchKernelGGL(fused_gvp_kernel, dim3(GRID), dim3(NTHREADS), 0, stream,
                       indice, lpos, tpos, lrad, trad, lnm, tnm, hcat,
                       AW1, Ab1, AW2, Ab2, BW1, Bb1, BW2, Bb2, ws);
    hipLaunchKernelGGL(finalize_kernel, dim3(1), dim3(NTHREADS), 0, stream,
                       ws, rotor, hbc, hyc, rcc, out);
}